// Round 8
// baseline (78.969 us; speedup 1.0000x reference)
//
#include <hip/hip_runtime.h>

#define NHEADS 4
#define HDIM   64
#define BATCH  8
#define SEQ    1024
#define CH     256   // H*hd = in_dim = out_dim
#define LOG2E  1.4426950408889634f

typedef float  f32x4  __attribute__((ext_vector_type(4)));
typedef __bf16 bf16x8 __attribute__((ext_vector_type(8)));
typedef short  s16x8  __attribute__((ext_vector_type(8)));
union FU { s16x8 s; bf16x8 b; };

__device__ inline unsigned short f2bf(float f) {
    unsigned u = __float_as_uint(f);
    return (unsigned short)((u + 0x7fffu + ((u >> 16) & 1u)) >> 16);
}

// ---------------------------------------------------------------------------
// K0: WpT[ch][k] = bf16(Wp[k][ch])   (256x256, tiny)
// ---------------------------------------------------------------------------
__global__ __launch_bounds__(256) void wpt_cast(const float* __restrict__ Wp,
                                                unsigned short* __restrict__ WpT) {
    __shared__ float T[32][33];
    const int t = threadIdx.x;
    const int kt = blockIdx.x * 32, ct = blockIdx.y * 32;
    const int r = t >> 3, c4 = (t & 7) * 4;
    float4 v = *reinterpret_cast<const float4*>(&Wp[(size_t)(kt + r) * CH + ct + c4]);
    T[r][c4 + 0] = v.x; T[r][c4 + 1] = v.y; T[r][c4 + 2] = v.z; T[r][c4 + 3] = v.w;
    __syncthreads();
    unsigned p0 = (unsigned)f2bf(T[c4 + 0][r]) | ((unsigned)f2bf(T[c4 + 1][r]) << 16);
    unsigned p1 = (unsigned)f2bf(T[c4 + 2][r]) | ((unsigned)f2bf(T[c4 + 3][r]) << 16);
    uint2 o = make_uint2(p0, p1);
    *reinterpret_cast<uint2*>(&WpT[(size_t)(ct + r) * CH + kt + c4]) = o;
}

// ---------------------------------------------------------------------------
// K1: projT = (x @ Wp)^T via MFMA. Block = 16 x-rows, wave w = head w.
//     Writes projT bf16 [b][h][d][m] + sl/sr (pre-scaled by log2e).
// ---------------------------------------------------------------------------
__global__ __launch_bounds__(256) void proj_fused(const float* __restrict__ x,
                                                  const unsigned short* __restrict__ WpT,
                                                  const float* __restrict__ Ws,
                                                  unsigned short* __restrict__ projT,
                                                  float* __restrict__ sl,
                                                  float* __restrict__ sr) {
    const int t = threadIdx.x, w = t >> 6, l = t & 63, il = l & 15, g = l >> 4;
    const int row0 = blockIdx.x * 16;           // global x row (= b*1024 + n0)
    const int b = row0 >> 10, n0 = row0 & 1023;

    const unsigned short* Ap = WpT + (size_t)(w * 64 + il) * CH + g * 8;
    const float*          Bp = x + (size_t)(row0 + il) * CH + g * 8;

    f32x4 acc[4] = {};   // [ai(ch group)]
#pragma unroll
    for (int kt = 0; kt < 8; ++kt) {
        FU a[4], bb;
#pragma unroll
        for (int ai = 0; ai < 4; ++ai)
            a[ai].s = *reinterpret_cast<const s16x8*>(Ap + (size_t)ai * 16 * CH + kt * 32);
        float4 v0 = *reinterpret_cast<const float4*>(Bp + kt * 32);
        float4 v1 = *reinterpret_cast<const float4*>(Bp + kt * 32 + 4);
        bb.b[0] = (__bf16)v0.x; bb.b[1] = (__bf16)v0.y;
        bb.b[2] = (__bf16)v0.z; bb.b[3] = (__bf16)v0.w;
        bb.b[4] = (__bf16)v1.x; bb.b[5] = (__bf16)v1.y;
        bb.b[6] = (__bf16)v1.z; bb.b[7] = (__bf16)v1.w;
#pragma unroll
        for (int ai = 0; ai < 4; ++ai)
            acc[ai] = __builtin_amdgcn_mfma_f32_16x16x32_bf16(a[ai].b, bb.b, acc[ai], 0, 0, 0);
    }

    unsigned short* pTb = projT + ((size_t)(b * NHEADS + w) * HDIM) * SEQ + n0 + il;
#pragma unroll
    for (int ai = 0; ai < 4; ++ai)
#pragma unroll
        for (int q = 0; q < 4; ++q)
            pTb[(size_t)(ai * 16 + g * 4 + q) * SEQ] = f2bf(acc[ai][q]);

    float pl = 0.f, pr = 0.f;
#pragma unroll
    for (int ai = 0; ai < 4; ++ai) {
        float4 wlv = *reinterpret_cast<const float4*>(&Ws[ai * 16 + g * 4]);
        float4 wrv = *reinterpret_cast<const float4*>(&Ws[HDIM + ai * 16 + g * 4]);
        pl += acc[ai][0] * wlv.x + acc[ai][1] * wlv.y + acc[ai][2] * wlv.z + acc[ai][3] * wlv.w;
        pr += acc[ai][0] * wrv.x + acc[ai][1] * wrv.y + acc[ai][2] * wrv.z + acc[ai][3] * wrv.w;
    }
    pl += __shfl_xor(pl, 16); pl += __shfl_xor(pl, 32);
    pr += __shfl_xor(pr, 16); pr += __shfl_xor(pr, 32);
    if (l < 16) {
        sl[(size_t)(b * NHEADS + w) * SEQ + n0 + il] = pl * LOG2E;
        sr[(size_t)(b * NHEADS + w) * SEQ + n0 + il] = pr * LOG2E;
    }
}

// ---------------------------------------------------------------------------
// K3: fused attention v5. Block = (i-tile 16, b), 512 threads = 8 waves:
//     wave w -> (head h = w&3, m-half mh = w>>2). Each wave owns 512 m values
//     FULLY INDEPENDENTLY: direct per-lane adj reads in A-frag layout, no LDS,
//     no barriers in the main loop (one barrier for the final half-combine).
//     den via ones-MFMA (same C-layout). Coalesced adj->out_adj copy is folded
//     in as an independent slice copy: block owns 16384 floats (= SEQ^2/64),
//     8 iters x 512 threads x 1 float4 = 4096 float4.  (R7 bug: 4x overrun.)
// ---------------------------------------------------------------------------
template <bool FUSE_ADJ>
__global__ __launch_bounds__(512, 4) void attn5(const float* __restrict__ x,
                                                const float* __restrict__ adj,
                                                const unsigned short* __restrict__ projT,
                                                const float* __restrict__ sl,
                                                const float* __restrict__ sr,
                                                const float* __restrict__ Ws,
                                                const float* __restrict__ bias,
                                                float* __restrict__ out,
                                                float* __restrict__ out_adj) {
    __shared__ float comb[NHEADS][16][68];   // [h][i-row][64 ch + den@64]

    const int t  = threadIdx.x;
    const int w  = t >> 6, l = t & 63, il = l & 15, g = l >> 4;
    const int h  = w & 3, mh = w >> 2;
    const int i0 = blockIdx.x * 16;
    const int b  = blockIdx.y;
    const float wa2 = Ws[2 * HDIM] * LOG2E;

    const float sl_i = sl[(size_t)(b * NHEADS + h) * SEQ + i0 + il];
    const float* srp = sr + (size_t)(b * NHEADS + h) * SEQ + mh * 512;
    const unsigned short* pT = projT + ((size_t)(b * NHEADS + h) * HDIM + il) * SEQ + mh * 512 + g * 8;
    const size_t arow = ((size_t)(b * SEQ + i0 + il)) * SEQ + mh * 512 + g * 8;

    // coalesced adj copy slice: 16384 floats per block (SEQ*SEQ/64)
    const size_t cbase = ((size_t)b << 20) + (size_t)blockIdx.x * 16384;
    const float4* csrc = reinterpret_cast<const float4*>(adj + cbase);
    float4*       cdst = reinterpret_cast<float4*>(out_adj + cbase);

    FU ones;
#pragma unroll
    for (int j = 0; j < 8; ++j) ones.s[j] = (short)0x3F80;   // bf16 1.0

    f32x4 acc[4] = {};
    f32x4 dacc = {};

    for (int s2 = 0; s2 < 8; ++s2) {        // 2 m-steps of 32 per iteration
        const int mt0 = s2 * 64;
        // batch the adj + sr loads for both sub-steps up front (ILP)
        float4 A[2][2], S[2][2];
#pragma unroll
        for (int u = 0; u < 2; ++u) {
            const int mt = mt0 + u * 32;
            A[u][0] = *reinterpret_cast<const float4*>(adj + arow + mt);
            A[u][1] = *reinterpret_cast<const float4*>(adj + arow + mt + 4);
            S[u][0] = *reinterpret_cast<const float4*>(srp + mt + g * 8);
            S[u][1] = *reinterpret_cast<const float4*>(srp + mt + g * 8 + 4);
        }
        // independent coalesced copy chunk (1 float4 / thread / iter)
        float4 C;
        if (FUSE_ADJ) C = csrc[s2 * 512 + t];
#pragma unroll
        for (int u = 0; u < 2; ++u) {
            const int mt = mt0 + u * 32;
            FU b0, b1, b2, b3;
            b0.s = *reinterpret_cast<const s16x8*>(pT + mt);
            b1.s = *reinterpret_cast<const s16x8*>(pT + mt + (size_t)16 * SEQ);
            b2.s = *reinterpret_cast<const s16x8*>(pT + mt + (size_t)32 * SEQ);
            b3.s = *reinterpret_cast<const s16x8*>(pT + mt + (size_t)48 * SEQ);
            float aj[8] = {A[u][0].x, A[u][0].y, A[u][0].z, A[u][0].w,
                           A[u][1].x, A[u][1].y, A[u][1].z, A[u][1].w};
            float sv[8] = {S[u][0].x, S[u][0].y, S[u][0].z, S[u][0].w,
                           S[u][1].x, S[u][1].y, S[u][1].z, S[u][1].w};
            FU af;
#pragma unroll
            for (int j = 0; j < 8; ++j) {
                float s = fmaf(aj[j], wa2, sl_i + sv[j]);
                s = __builtin_amdgcn_fmed3f(s, 0.2f * s, 86.5617f);   // lrelu + clamp
                float e = (aj[j] <= 1e-5f) ? 0.f : __builtin_amdgcn_exp2f(s);
                af.b[j] = (__bf16)e;
            }
            acc[0] = __builtin_amdgcn_mfma_f32_16x16x32_bf16(af.b, b0.b, acc[0], 0, 0, 0);
            acc[1] = __builtin_amdgcn_mfma_f32_16x16x32_bf16(af.b, b1.b, acc[1], 0, 0, 0);
            acc[2] = __builtin_amdgcn_mfma_f32_16x16x32_bf16(af.b, b2.b, acc[2], 0, 0, 0);
            acc[3] = __builtin_amdgcn_mfma_f32_16x16x32_bf16(af.b, b3.b, acc[3], 0, 0, 0);
            dacc   = __builtin_amdgcn_mfma_f32_16x16x32_bf16(af.b, ones.b, dacc, 0, 0, 0);
        }
        if (FUSE_ADJ) cdst[s2 * 512 + t] = C;
    }

    // cross-half combine: mh==1 dumps, mh==0 finalizes
    if (mh == 1) {
#pragma unroll
        for (int bj = 0; bj < 4; ++bj)
#pragma unroll
            for (int q = 0; q < 4; ++q)
                comb[h][g * 4 + q][bj * 16 + il] = acc[bj][q];
        if (il == 0) {
#pragma unroll
            for (int q = 0; q < 4; ++q) comb[h][g * 4 + q][64] = dacc[q];
        }
    }
    __syncthreads();
    if (mh == 0) {
        const float* bb = bias + h * HDIM;
#pragma unroll
        for (int q = 0; q < 4; ++q) {
            const int row = g * 4 + q;
            const float den = dacc[q] + comb[h][row][64];
            const float inv = 1.f / den;
            const size_t ob = ((size_t)(b * SEQ + i0 + row)) * CH + h * HDIM + il;
#pragma unroll
            for (int bj = 0; bj < 4; ++bj) {
                float m = acc[bj][q] + comb[h][row][bj * 16 + il];
                float v = fmaf(m, inv, x[ob + bj * 16] + bb[bj * 16 + il]);
                out[ob + bj * 16] = fmaxf(v, 0.5f * v);
            }
        }
    }
}

// ---------------------------------------------------------------------------
// K4 (fallback): copy adj into output chunk 2
// ---------------------------------------------------------------------------
__global__ void adjcopy(const float* __restrict__ adj, float* __restrict__ dst, int n4) {
    int idx = blockIdx.x * blockDim.x + threadIdx.x;
    int stride = gridDim.x * blockDim.x;
    const float4* s = reinterpret_cast<const float4*>(adj);
    float4* d = reinterpret_cast<float4*>(dst);
    for (int i = idx; i < n4; i += stride) d[i] = s[i];
}

extern "C" void kernel_launch(void* const* d_in, const int* in_sizes, int n_in,
                              void* d_out, int out_size, void* d_ws, size_t ws_size,
                              hipStream_t stream) {
    const float* x    = (const float*)d_in[0];
    const float* adj  = (const float*)d_in[1];
    const float* Wp   = (const float*)d_in[2];
    const float* Ws   = (const float*)d_in[3];
    const float* bias = (const float*)d_in[4];
    float* out     = (float*)d_out;
    float* out_adj = out + (size_t)BATCH * SEQ * CH;

    // scratch: WpT bf16 (128KB) + projT bf16 (4MB) + sl + sr (128KB each)
    const size_t nProj = (size_t)BATCH * SEQ * CH;
    const size_t nSc   = (size_t)BATCH * NHEADS * SEQ;
    const size_t need  = CH * CH * 2 + nProj * 2 + 2 * nSc * 4;
    const bool use_ws  = (ws_size >= need);
    char* scratch = use_ws ? (char*)d_ws : (char*)out_adj;
    unsigned short* WpT   = (unsigned short*)scratch;
    unsigned short* projT = (unsigned short*)(scratch + (size_t)CH * CH * 2);
    float*          sl    = (float*)(scratch + (size_t)CH * CH * 2 + nProj * 2);
    float*          sr    = sl + nSc;

    wpt_cast<<<dim3(8, 8), 256, 0, stream>>>(Wp, WpT);
    proj_fused<<<dim3(512), 256, 0, stream>>>(x, WpT, Ws, projT, sl, sr);
    if (use_ws) {
        attn5<true><<<dim3(SEQ / 16, BATCH), 512, 0, stream>>>(
            x, adj, projT, sl, sr, Ws, bias, out, out_adj);
    } else {
        attn5<false><<<dim3(SEQ / 16, BATCH), 512, 0, stream>>>(
            x, adj, projT, sl, sr, Ws, bias, out, out_adj);
        adjcopy<<<2048, 256, 0, stream>>>(adj, out_adj, (BATCH * SEQ * SEQ) / 4);
    }
}